// Round 1
// baseline (1166.789 us; speedup 1.0000x reference)
//
#include <hip/hip_runtime.h>
#include <stdint.h>

#define V_SZ   1000000
#define N0_SZ  1048576
#define N1_SZ  131072
#define N2_SZ  16384
#define E0_SZ  1048576
#define E1_SZ  131072
#define EP_SZ  16384

typedef short bf16x8 __attribute__((ext_vector_type(8)));
typedef float f32x4  __attribute__((ext_vector_type(4)));

__device__ __forceinline__ unsigned short f2bf(float f) {
  union { float f; unsigned u; } v; v.f = f;
  unsigned r = v.u + 0x7FFFu + ((v.u >> 16) & 1u);   // RNE
  return (unsigned short)(r >> 16);
}
__device__ __forceinline__ float bf2f(unsigned short h) {
  union { unsigned u; float f; } v; v.u = ((unsigned)h) << 16;
  return v.f;
}

// ---------- weight prep: W (K x 128, f32 row-major) -> WT (128 x K, bf16, n-major)
__global__ __launch_bounds__(256) void prepw_k(const float* __restrict__ W,
                                               unsigned short* __restrict__ WT, int K) {
  int t = blockIdx.x * 256 + threadIdx.x;
  if (t >= K * 128) return;
  int n = t & 127, k = t >> 7;
  WT[(size_t)n * K + k] = f2bf(W[t]);
}

// ---------- CSR build ----------
__global__ __launch_bounds__(256) void hist_k(const int* __restrict__ dst, int E,
                                              int* __restrict__ counts) {
  int e = blockIdx.x * 256 + threadIdx.x;
  if (e < E) atomicAdd(&counts[dst[e]], 1);
}

// per-block (1024 elems) sums
__global__ __launch_bounds__(256) void scan_bsums_k(const int* __restrict__ counts,
                                                    int* __restrict__ bsums) {
  __shared__ int red[256];
  int base = blockIdx.x * 1024, t = threadIdx.x;
  int s = 0;
  #pragma unroll
  for (int i = 0; i < 4; i++) s += counts[base + t * 4 + i];
  red[t] = s;
  __syncthreads();
  for (int st = 128; st > 0; st >>= 1) {
    if (t < st) red[t] += red[t + st];
    __syncthreads();
  }
  if (t == 0) bsums[blockIdx.x] = red[0];
}

// exclusive scan of block sums (nb <= 256), writes grand total to offs_last
__global__ __launch_bounds__(256) void scan_top_k(int* __restrict__ bsums, int nb,
                                                  int* __restrict__ offs_last) {
  __shared__ int lds[256];
  int t = threadIdx.x;
  int v = (t < nb) ? bsums[t] : 0;
  lds[t] = v;
  __syncthreads();
  for (int st = 1; st < 256; st <<= 1) {
    int x = (t >= st) ? lds[t - st] : 0;
    __syncthreads();
    lds[t] += x;
    __syncthreads();
  }
  if (t < nb) bsums[t] = lds[t] - v;       // exclusive
  if (t == nb - 1) *offs_last = lds[t];    // total
}

// final: exclusive scan within each 1024 chunk + add block prefix
__global__ __launch_bounds__(256) void scan_final_k(const int* __restrict__ counts,
                                                    const int* __restrict__ bsums,
                                                    int* __restrict__ offs) {
  __shared__ int tsum[256];
  int base = blockIdx.x * 1024, t = threadIdx.x;
  int v0 = counts[base + t * 4 + 0], v1 = counts[base + t * 4 + 1];
  int v2 = counts[base + t * 4 + 2], v3 = counts[base + t * 4 + 3];
  int s = v0 + v1 + v2 + v3;
  tsum[t] = s;
  __syncthreads();
  for (int st = 1; st < 256; st <<= 1) {
    int x = (t >= st) ? tsum[t - st] : 0;
    __syncthreads();
    tsum[t] += x;
    __syncthreads();
  }
  int pre = bsums[blockIdx.x] + tsum[t] - s;
  offs[base + t * 4 + 0] = pre;
  offs[base + t * 4 + 1] = pre + v0;
  offs[base + t * 4 + 2] = pre + v0 + v1;
  offs[base + t * 4 + 3] = pre + v0 + v1 + v2;
}

__global__ __launch_bounds__(256) void scatter_k(const int* __restrict__ src,
                                                 const int* __restrict__ dst,
                                                 const float* __restrict__ w, int E,
                                                 const int* __restrict__ offs,
                                                 int* __restrict__ cursor,
                                                 int* __restrict__ srcs_s,
                                                 float* __restrict__ ws_s) {
  int e = blockIdx.x * 256 + threadIdx.x;
  if (e >= E) return;
  int d = dst[e];
  int p = offs[d] + atomicAdd(&cursor[d], 1);
  srcs_s[p] = src[e];
  ws_s[p] = w[e];
}

// ---------- fused gather-GEMM (rows x 128, K = 128*KCHUNKS) ----------
#define AM_GATHER 0   // A chunk: fp32 rows gathered via ids, converted bf16
#define AM_BF16   1   // A chunk: contiguous bf16 rows
#define EPI_BF16        0  // relu -> bf16 store
#define EPI_NORM        1  // relu -> row L2-normalize -> bf16 store
#define EPI_NORM_ADDEMB 2  // relu -> normalize -> + emb[ids[row]] -> f32 store

template <int KCHUNKS, int AM0, int AM1, int EPI>
__global__ __launch_bounds__(256) void gemm_k(const void* __restrict__ asrc0,
                                              const void* __restrict__ asrc1,
                                              const int* __restrict__ ids,
                                              const unsigned short* __restrict__ BT,
                                              const float* __restrict__ biasv,
                                              void* __restrict__ outp,
                                              const float* __restrict__ emb) {
  __shared__ unsigned short lA[64][136];   // +8 pad: 2-way max bank conflict on b128
  __shared__ unsigned short lB[128][136];
  const int tid = threadIdx.x;
  const int lane = tid & 63;
  const int wid = tid >> 6;
  const int rowbase = blockIdx.x * 64;
  const int Ktot = KCHUNKS * 128;

  f32x4 acc[8];
  #pragma unroll
  for (int i = 0; i < 8; i++) acc[i] = (f32x4){0.f, 0.f, 0.f, 0.f};

  for (int c = 0; c < KCHUNKS; ++c) {
    if (c) __syncthreads();
    const int am = (c == 0) ? AM0 : AM1;
    const void* asrc = (c == 0) ? asrc0 : asrc1;
    if (am == AM_GATHER) {
      const float* fsrc = (const float*)asrc;
      #pragma unroll
      for (int i = 0; i < 8; i++) {
        int f = i * 256 + tid;
        int r = f >> 5, c4 = f & 31;          // two full rows per wave-instr
        const float* rp = fsrc + (size_t)ids[rowbase + r] * 128;
        float4 v = *(const float4*)(rp + c4 * 4);
        unsigned short* pp = &lA[r][c4 * 4];
        pp[0] = f2bf(v.x); pp[1] = f2bf(v.y); pp[2] = f2bf(v.z); pp[3] = f2bf(v.w);
      }
    } else {
      const unsigned short* bsrc = (const unsigned short*)asrc;
      #pragma unroll
      for (int i = 0; i < 4; i++) {
        int f = i * 256 + tid;
        int r = f >> 4, c8 = f & 15;
        uint4 v = *(const uint4*)(bsrc + (size_t)(rowbase + r) * 128 + c8 * 8);
        *(uint4*)(&lA[r][c8 * 8]) = v;
      }
    }
    {
      const unsigned short* bp = BT + c * 128;
      #pragma unroll
      for (int i = 0; i < 8; i++) {
        int f = i * 256 + tid;
        int n = f >> 4, c8 = f & 15;
        uint4 v = *(const uint4*)(bp + (size_t)n * Ktot + c8 * 8);
        *(uint4*)(&lB[n][c8 * 8]) = v;
      }
    }
    __syncthreads();

    const int mr = wid * 16 + (lane & 15);
    const int kq = (lane >> 4) * 8;
    #pragma unroll
    for (int kk = 0; kk < 128; kk += 32) {
      bf16x8 af = *(const bf16x8*)(&lA[mr][kk + kq]);
      #pragma unroll
      for (int nt = 0; nt < 8; ++nt) {
        bf16x8 bfr = *(const bf16x8*)(&lB[nt * 16 + (lane & 15)][kk + kq]);
        acc[nt] = __builtin_amdgcn_mfma_f32_16x16x32_bf16(af, bfr, acc[nt], 0, 0, 0);
      }
    }
  }

  // epilogue: C/D layout col=lane&15 (+16*nt), row=(lane>>4)*4+r
  const int crow = wid * 16 + ((lane >> 4) << 2);
  float vreg[8][4];
  #pragma unroll
  for (int nt = 0; nt < 8; ++nt) {
    int col = nt * 16 + (lane & 15);
    float b = biasv[col];
    #pragma unroll
    for (int r = 0; r < 4; ++r) {
      float v = acc[nt][r] + b;
      vreg[nt][r] = v > 0.f ? v : 0.f;
    }
  }
  if (EPI == EPI_BF16) {
    unsigned short* op = (unsigned short*)outp;
    #pragma unroll
    for (int nt = 0; nt < 8; ++nt) {
      int col = nt * 16 + (lane & 15);
      #pragma unroll
      for (int r = 0; r < 4; ++r)
        op[(size_t)(rowbase + crow + r) * 128 + col] = f2bf(vreg[nt][r]);
    }
  } else {
    float ss[4] = {0.f, 0.f, 0.f, 0.f};
    #pragma unroll
    for (int nt = 0; nt < 8; ++nt)
      #pragma unroll
      for (int r = 0; r < 4; ++r) ss[r] += vreg[nt][r] * vreg[nt][r];
    #pragma unroll
    for (int r = 0; r < 4; ++r) {
      ss[r] += __shfl_xor(ss[r], 1);
      ss[r] += __shfl_xor(ss[r], 2);
      ss[r] += __shfl_xor(ss[r], 4);
      ss[r] += __shfl_xor(ss[r], 8);
    }
    float sc[4];
    #pragma unroll
    for (int r = 0; r < 4; ++r) sc[r] = ss[r] > 0.f ? rsqrtf(ss[r]) : 1.0f;
    if (EPI == EPI_NORM) {
      unsigned short* op = (unsigned short*)outp;
      #pragma unroll
      for (int nt = 0; nt < 8; ++nt) {
        int col = nt * 16 + (lane & 15);
        #pragma unroll
        for (int r = 0; r < 4; ++r)
          op[(size_t)(rowbase + crow + r) * 128 + col] = f2bf(vreg[nt][r] * sc[r]);
      }
    } else {
      float* op = (float*)outp;
      #pragma unroll
      for (int nt = 0; nt < 8; ++nt) {
        int col = nt * 16 + (lane & 15);
        #pragma unroll
        for (int r = 0; r < 4; ++r) {
          int row = rowbase + crow + r;
          op[(size_t)row * 128 + col] =
              vreg[nt][r] * sc[r] + emb[(size_t)ids[row] * 128 + col];
        }
      }
    }
  }
}

// ---------- CSR aggregation: one wave per dst, m/ws -> bf16 ----------
__global__ __launch_bounds__(256) void agg_k(const unsigned short* __restrict__ nsrc,
                                             const int* __restrict__ offs,
                                             const int* __restrict__ srcs_s,
                                             const float* __restrict__ ws_s,
                                             unsigned short* __restrict__ aout, int ndst) {
  int wid = threadIdx.x >> 6, lane = threadIdx.x & 63;
  int d = blockIdx.x * 4 + wid;
  if (d >= ndst) return;
  int beg = offs[d], end = offs[d + 1];
  float ax = 0.f, ay = 0.f, wsum = 0.f;
  for (int j = beg; j < end; ++j) {
    int s = srcs_s[j];
    float w = ws_s[j];
    unsigned u = *(const unsigned*)(nsrc + (size_t)s * 128 + lane * 2);
    ax += w * bf2f((unsigned short)(u & 0xffff));
    ay += w * bf2f((unsigned short)(u >> 16));
    wsum += w;
  }
  float inv = 1.0f / fmaxf(wsum, 1.0f);
  unsigned o = ((unsigned)f2bf(ay * inv) << 16) | (unsigned)f2bf(ax * inv);
  *(unsigned*)(aout + (size_t)d * 128 + lane * 2) = o;
}

// ---------- misc ----------
__global__ __launch_bounds__(256) void gatherbias_k(const float* __restrict__ bias,
                                                    const int* __restrict__ nids,
                                                    float* __restrict__ biasg) {
  int i = blockIdx.x * 256 + threadIdx.x;
  if (i < N2_SZ) biasg[i] = bias[nids[i]];
}

__global__ __launch_bounds__(256) void score_k(const float* __restrict__ hitem,
                                               const float* __restrict__ biasg,
                                               const int* __restrict__ ps,
                                               const int* __restrict__ pd,
                                               const int* __restrict__ ns,
                                               const int* __restrict__ nd,
                                               float* __restrict__ out) {
  int wid = threadIdx.x >> 6, lane = threadIdx.x & 63;
  int e = blockIdx.x * 4 + wid;
  if (e >= EP_SZ) return;
  int a = ps[e], b = pd[e], c = ns[e], d = nd[e];
  float2 va = ((const float2*)(hitem + (size_t)a * 128))[lane];
  float2 vb = ((const float2*)(hitem + (size_t)b * 128))[lane];
  float2 vc = ((const float2*)(hitem + (size_t)c * 128))[lane];
  float2 vd = ((const float2*)(hitem + (size_t)d * 128))[lane];
  float dp = va.x * vb.x + va.y * vb.y;
  float dn = vc.x * vd.x + vc.y * vd.y;
  #pragma unroll
  for (int m = 1; m < 64; m <<= 1) {
    dp += __shfl_xor(dp, m);
    dn += __shfl_xor(dn, m);
  }
  if (lane == 0) {
    float sp = dp + biasg[a] + biasg[b];
    float sn = dn + biasg[c] + biasg[d];
    out[e] = fmaxf(sn - sp + 1.0f, 0.0f);
  }
}

extern "C" void kernel_launch(void* const* d_in, const int* in_sizes, int n_in,
                              void* d_out, int out_size, void* d_ws, size_t ws_size,
                              hipStream_t stream) {
  const float* emb  = (const float*)d_in[0];
  const float* bias = (const float*)d_in[1];
  const int* nids   = (const int*)d_in[2];
  const int* src0   = (const int*)d_in[3];
  const int* dst0   = (const int*)d_in[4];
  const float* w0   = (const float*)d_in[5];
  const int* src1   = (const int*)d_in[6];
  const int* dst1   = (const int*)d_in[7];
  const float* w1   = (const float*)d_in[8];
  const int* pos_src = (const int*)d_in[9];
  const int* pos_dst = (const int*)d_in[10];
  const int* neg_src = (const int*)d_in[11];
  const int* neg_dst = (const int*)d_in[12];
  const float* Q0w = (const float*)d_in[13];
  const float* Q0b = (const float*)d_in[14];
  const float* W0w = (const float*)d_in[15];
  const float* W0b = (const float*)d_in[16];
  const float* Q1w = (const float*)d_in[17];
  const float* Q1b = (const float*)d_in[18];
  const float* W1w = (const float*)d_in[19];
  const float* W1b = (const float*)d_in[20];
  float* out = (float*)d_out;

  char* ws = (char*)d_ws;
  size_t p = 0;
  auto carve = [&](size_t sz) { void* r = ws + p; p = (p + sz + 255) & ~(size_t)255; return r; };

  // Region R: 256 MB, n0 during phase A then reused for phase-B buffers.
  unsigned short* n0 = (unsigned short*)carve((size_t)N0_SZ * 128 * 2);  // 256 MB @0
  unsigned short* h1    = (unsigned short*)(ws + 0);
  unsigned short* n1    = (unsigned short*)(ws + 33554432);
  unsigned short* a1    = (unsigned short*)(ws + 67108864);
  float*          hitem = (float*)(ws + 71303168);
  float*          biasg = (float*)(ws + 79691776);

  unsigned short* a0  = (unsigned short*)carve((size_t)N1_SZ * 128 * 2);  // 32 MB
  unsigned short* Q0T = (unsigned short*)carve(128 * 128 * 2);
  unsigned short* W0T = (unsigned short*)carve(256 * 128 * 2);
  unsigned short* Q1T = (unsigned short*)carve(128 * 128 * 2);
  unsigned short* W1T = (unsigned short*)carve(256 * 128 * 2);
  int*   counts0 = (int*)carve(N1_SZ * 4);
  int*   offs0   = (int*)carve((N1_SZ + 1) * 4);
  int*   cursor0 = (int*)carve(N1_SZ * 4);
  int*   srcs_s0 = (int*)carve(E0_SZ * 4);
  float* ws_s0   = (float*)carve(E0_SZ * 4);
  int*   counts1 = (int*)carve(N2_SZ * 4);
  int*   offs1   = (int*)carve((N2_SZ + 1) * 4);
  int*   cursor1 = (int*)carve(N2_SZ * 4);
  int*   srcs_s1 = (int*)carve(E1_SZ * 4);
  float* ws_s1   = (float*)carve(E1_SZ * 4);
  int*   bsums0  = (int*)carve(128 * 4);
  int*   bsums1  = (int*)carve(16 * 4);
  (void)ws_size; (void)in_sizes; (void)n_in; (void)out_size;

  hipMemsetAsync(counts0, 0, N1_SZ * 4, stream);
  hipMemsetAsync(cursor0, 0, N1_SZ * 4, stream);
  hipMemsetAsync(counts1, 0, N2_SZ * 4, stream);
  hipMemsetAsync(cursor1, 0, N2_SZ * 4, stream);

  prepw_k<<<64, 256, 0, stream>>>(Q0w, Q0T, 128);
  prepw_k<<<128, 256, 0, stream>>>(W0w, W0T, 256);
  prepw_k<<<64, 256, 0, stream>>>(Q1w, Q1T, 128);
  prepw_k<<<128, 256, 0, stream>>>(W1w, W1T, 256);

  // CSR layer 0
  hist_k<<<E0_SZ / 256, 256, 0, stream>>>(dst0, E0_SZ, counts0);
  scan_bsums_k<<<N1_SZ / 1024, 256, 0, stream>>>(counts0, bsums0);
  scan_top_k<<<1, 256, 0, stream>>>(bsums0, N1_SZ / 1024, offs0 + N1_SZ);
  scan_final_k<<<N1_SZ / 1024, 256, 0, stream>>>(counts0, bsums0, offs0);
  scatter_k<<<E0_SZ / 256, 256, 0, stream>>>(src0, dst0, w0, E0_SZ, offs0, cursor0, srcs_s0, ws_s0);
  // CSR layer 1
  hist_k<<<E1_SZ / 256, 256, 0, stream>>>(dst1, E1_SZ, counts1);
  scan_bsums_k<<<N2_SZ / 1024, 256, 0, stream>>>(counts1, bsums1);
  scan_top_k<<<1, 256, 0, stream>>>(bsums1, N2_SZ / 1024, offs1 + N2_SZ);
  scan_final_k<<<N2_SZ / 1024, 256, 0, stream>>>(counts1, bsums1, offs1);
  scatter_k<<<E1_SZ / 256, 256, 0, stream>>>(src1, dst1, w1, E1_SZ, offs1, cursor1, srcs_s1, ws_s1);

  // n0 = relu(bf16(emb[nids]) @ Q0 + Q0b)
  gemm_k<1, AM_GATHER, AM_GATHER, EPI_BF16>
      <<<N0_SZ / 64, 256, 0, stream>>>(emb, nullptr, nids, Q0T, Q0b, n0, nullptr);
  // a0 = segsum(w*n0)/max(segsum(w),1)
  agg_k<<<N1_SZ / 4, 256, 0, stream>>>(n0, offs0, srcs_s0, ws_s0, a0, N1_SZ);
  // h1 = rownorm(relu([a0, emb[nids[:N1]]] @ W0 + W0b))
  gemm_k<2, AM_BF16, AM_GATHER, EPI_NORM>
      <<<N1_SZ / 64, 256, 0, stream>>>(a0, emb, nids, W0T, W0b, h1, nullptr);
  // n1 = relu(h1 @ Q1 + Q1b)
  gemm_k<1, AM_BF16, AM_BF16, EPI_BF16>
      <<<N1_SZ / 64, 256, 0, stream>>>(h1, nullptr, nullptr, Q1T, Q1b, n1, nullptr);
  // a1
  agg_k<<<N2_SZ / 4, 256, 0, stream>>>(n1, offs1, srcs_s1, ws_s1, a1, N2_SZ);
  // hitem = rownorm(relu([a1, h1[:N2]] @ W1 + W1b)) + emb[nids[:N2]]
  gemm_k<2, AM_BF16, AM_BF16, EPI_NORM_ADDEMB>
      <<<N2_SZ / 64, 256, 0, stream>>>(a1, h1, nids, W1T, W1b, hitem, emb);

  gatherbias_k<<<N2_SZ / 256, 256, 0, stream>>>(bias, nids, biasg);
  score_k<<<EP_SZ / 4, 256, 0, stream>>>(hitem, biasg, pos_src, pos_dst,
                                         neg_src, neg_dst, out);
}

// Round 2
// 1040.849 us; speedup vs baseline: 1.1210x; 1.1210x over previous
//
#include <hip/hip_runtime.h>
#include <stdint.h>

#define V_SZ   1000000
#define N0_SZ  1048576
#define N1_SZ  131072
#define N2_SZ  16384
#define E0_SZ  1048576
#define E1_SZ  131072
#define EP_SZ  16384

typedef short bf16x8 __attribute__((ext_vector_type(8)));
typedef float f32x4  __attribute__((ext_vector_type(4)));

__device__ __forceinline__ unsigned short f2bf(float f) {
  union { float f; unsigned u; } v; v.f = f;
  unsigned r = v.u + 0x7FFFu + ((v.u >> 16) & 1u);   // RNE
  return (unsigned short)(r >> 16);
}
__device__ __forceinline__ float bf2f(unsigned short h) {
  union { unsigned u; float f; } v; v.u = ((unsigned)h) << 16;
  return v.f;
}
__device__ __forceinline__ unsigned pack2bf(float a, float b) {
  return ((unsigned)f2bf(b) << 16) | (unsigned)f2bf(a);
}

// ---------- merged weight prep: 4 weights f32 (K x 128) -> bf16 (128 x K) ----------
__global__ __launch_bounds__(256) void prepw_all_k(
    const float* __restrict__ Q0w, const float* __restrict__ W0w,
    const float* __restrict__ Q1w, const float* __restrict__ W1w,
    unsigned short* __restrict__ Q0T, unsigned short* __restrict__ W0T,
    unsigned short* __restrict__ Q1T, unsigned short* __restrict__ W1T) {
  int t = blockIdx.x * 256 + threadIdx.x;   // total 98304
  const float* W; unsigned short* WT; int K; int base;
  if (t < 16384)      { W = Q0w; WT = Q0T; K = 128; base = 0; }
  else if (t < 49152) { W = W0w; WT = W0T; K = 256; base = 16384; }
  else if (t < 65536) { W = Q1w; WT = Q1T; K = 128; base = 49152; }
  else                { W = W1w; WT = W1T; K = 256; base = 65536; }
  int u = t - base;
  int n = u & 127, k = u >> 7;
  WT[(size_t)n * K + k] = f2bf(W[u]);
}

// ---------- merged CSR build (both layers; counts0|counts1 contiguous) ----------
__global__ __launch_bounds__(256) void hist_all_k(const int* __restrict__ dst0,
                                                  const int* __restrict__ dst1,
                                                  int* __restrict__ counts) {
  int e = blockIdx.x * 256 + threadIdx.x;   // E0+E1
  if (e < E0_SZ) atomicAdd(&counts[dst0[e]], 1);
  else if (e < E0_SZ + E1_SZ) atomicAdd(&counts[N1_SZ + dst1[e - E0_SZ]], 1);
}

// per-1024-chunk sums over the combined counts array (144 blocks)
__global__ __launch_bounds__(256) void scan_bsums_k(const int* __restrict__ counts,
                                                    int* __restrict__ bsums) {
  __shared__ int red[256];
  int base = blockIdx.x * 1024, t = threadIdx.x;
  int s = 0;
  #pragma unroll
  for (int i = 0; i < 4; i++) s += counts[base + t * 4 + i];
  red[t] = s;
  __syncthreads();
  for (int st = 128; st > 0; st >>= 1) {
    if (t < st) red[t] += red[t + st];
    __syncthreads();
  }
  if (t == 0) bsums[blockIdx.x] = red[0];
}

// block 0: exclusive-scan bsums[0:128] (layer0); block 1: bsums[128:144] (layer1)
__global__ __launch_bounds__(256) void scan_top2_k(int* __restrict__ bsums,
                                                   int* __restrict__ offs0_last,
                                                   int* __restrict__ offs1_last) {
  __shared__ int lds[256];
  int b = blockIdx.x, t = threadIdx.x;
  int nb = (b == 0) ? 128 : 16;
  int off = (b == 0) ? 0 : 128;
  int v = (t < nb) ? bsums[off + t] : 0;
  lds[t] = v;
  __syncthreads();
  for (int st = 1; st < 256; st <<= 1) {
    int x = (t >= st) ? lds[t - st] : 0;
    __syncthreads();
    lds[t] += x;
    __syncthreads();
  }
  if (t < nb) bsums[off + t] = lds[t] - v;
  if (t == nb - 1) *((b == 0) ? offs0_last : offs1_last) = lds[t];
}

// final: exclusive scan within each 1024 chunk + add per-layer block prefix
__global__ __launch_bounds__(256) void scan_final_k(const int* __restrict__ counts,
                                                    const int* __restrict__ bsums,
                                                    int* __restrict__ offs0,
                                                    int* __restrict__ offs1) {
  __shared__ int tsum[256];
  int b = blockIdx.x, t = threadIdx.x;
  int base = b * 1024;
  int v0 = counts[base + t * 4 + 0], v1 = counts[base + t * 4 + 1];
  int v2 = counts[base + t * 4 + 2], v3 = counts[base + t * 4 + 3];
  int s = v0 + v1 + v2 + v3;
  tsum[t] = s;
  __syncthreads();
  for (int st = 1; st < 256; st <<= 1) {
    int x = (t >= st) ? tsum[t - st] : 0;
    __syncthreads();
    tsum[t] += x;
    __syncthreads();
  }
  int pre = bsums[b] + tsum[t] - s;
  int* op = (b < 128) ? (offs0 + base) : (offs1 + base - N1_SZ);
  op[t * 4 + 0] = pre;
  op[t * 4 + 1] = pre + v0;
  op[t * 4 + 2] = pre + v0 + v1;
  op[t * 4 + 3] = pre + v0 + v1 + v2;
}

__global__ __launch_bounds__(256) void scatter_all_k(
    const int* __restrict__ src0, const int* __restrict__ dst0, const float* __restrict__ w0,
    const int* __restrict__ src1, const int* __restrict__ dst1, const float* __restrict__ w1,
    const int* __restrict__ offs0, const int* __restrict__ offs1,
    int* __restrict__ cursor,                      // cursor0(N1) | cursor1(N2)
    int* __restrict__ srcs_s0, float* __restrict__ ws_s0,
    int* __restrict__ srcs_s1, float* __restrict__ ws_s1) {
  int e = blockIdx.x * 256 + threadIdx.x;
  if (e < E0_SZ) {
    int d = dst0[e];
    int p = offs0[d] + atomicAdd(&cursor[d], 1);
    srcs_s0[p] = src0[e];
    ws_s0[p] = w0[e];
  } else if (e < E0_SZ + E1_SZ) {
    int ee = e - E0_SZ;
    int d = dst1[ee];
    int p = offs1[d] + atomicAdd(&cursor[N1_SZ + d], 1);
    srcs_s1[p] = src1[ee];
    ws_s1[p] = w1[ee];
  }
}

// ---------- fused gather-GEMM (rows x 128, K = 128*KCHUNKS) ----------
#define AM_GATHER 0
#define AM_BF16   1
#define EPI_BF16        0
#define EPI_NORM        1
#define EPI_NORM_ADDEMB 2

template <int KCHUNKS, int AM0, int AM1, int EPI>
__global__ __launch_bounds__(256) void gemm_k(const void* __restrict__ asrc0,
                                              const void* __restrict__ asrc1,
                                              const int* __restrict__ ids,
                                              const unsigned short* __restrict__ BT,
                                              const float* __restrict__ biasv,
                                              void* __restrict__ outp,
                                              const float* __restrict__ emb) {
  __shared__ unsigned short lA[64][136];
  __shared__ unsigned short lB[128][136];
  const int tid = threadIdx.x;
  const int lane = tid & 63;
  const int wid = tid >> 6;
  const int rowbase = blockIdx.x * 64;
  const int Ktot = KCHUNKS * 128;

  f32x4 acc[8];
  #pragma unroll
  for (int i = 0; i < 8; i++) acc[i] = (f32x4){0.f, 0.f, 0.f, 0.f};

  for (int c = 0; c < KCHUNKS; ++c) {
    if (c) __syncthreads();
    const int am = (c == 0) ? AM0 : AM1;
    const void* asrc = (c == 0) ? asrc0 : asrc1;
    if (am == AM_GATHER) {
      const float* fsrc = (const float*)asrc;
      #pragma unroll
      for (int i = 0; i < 8; i++) {
        int f = i * 256 + tid;
        int r = f >> 5, c4 = f & 31;
        const float* rp = fsrc + (size_t)ids[rowbase + r] * 128;
        float4 v = *(const float4*)(rp + c4 * 4);
        uint2 pk;
        pk.x = pack2bf(v.x, v.y);
        pk.y = pack2bf(v.z, v.w);
        *(uint2*)(&lA[r][c4 * 4]) = pk;
      }
    } else {
      const unsigned short* bsrc = (const unsigned short*)asrc;
      #pragma unroll
      for (int i = 0; i < 4; i++) {
        int f = i * 256 + tid;
        int r = f >> 4, c8 = f & 15;
        uint4 v = *(const uint4*)(bsrc + (size_t)(rowbase + r) * 128 + c8 * 8);
        *(uint4*)(&lA[r][c8 * 8]) = v;
      }
    }
    {
      const unsigned short* bp = BT + c * 128;
      #pragma unroll
      for (int i = 0; i < 8; i++) {
        int f = i * 256 + tid;
        int n = f >> 4, c8 = f & 15;
        uint4 v = *(const uint4*)(bp + (size_t)n * Ktot + c8 * 8);
        *(uint4*)(&lB[n][c8 * 8]) = v;
      }
    }
    __syncthreads();

    const int mr = wid * 16 + (lane & 15);
    const int kq = (lane >> 4) * 8;
    #pragma unroll
    for (int kk = 0; kk < 128; kk += 32) {
      bf16x8 af = *(const bf16x8*)(&lA[mr][kk + kq]);
      #pragma unroll
      for (int nt = 0; nt < 8; ++nt) {
        bf16x8 bfr = *(const bf16x8*)(&lB[nt * 16 + (lane & 15)][kk + kq]);
        acc[nt] = __builtin_amdgcn_mfma_f32_16x16x32_bf16(af, bfr, acc[nt], 0, 0, 0);
      }
    }
  }

  // epilogue: C/D layout col=lane&15 (+16*nt), row=(lane>>4)*4+r
  const int crow = wid * 16 + ((lane >> 4) << 2);
  float vreg[8][4];
  #pragma unroll
  for (int nt = 0; nt < 8; ++nt) {
    int col = nt * 16 + (lane & 15);
    float b = biasv[col];
    #pragma unroll
    for (int r = 0; r < 4; ++r) {
      float v = acc[nt][r] + b;
      vreg[nt][r] = v > 0.f ? v : 0.f;
    }
  }
  if (EPI == EPI_BF16) {
    unsigned short* op = (unsigned short*)outp;
    #pragma unroll
    for (int nt = 0; nt < 8; ++nt) {
      int col = nt * 16 + (lane & 15);
      #pragma unroll
      for (int r = 0; r < 4; ++r)
        op[(size_t)(rowbase + crow + r) * 128 + col] = f2bf(vreg[nt][r]);
    }
  } else {
    float ss[4] = {0.f, 0.f, 0.f, 0.f};
    #pragma unroll
    for (int nt = 0; nt < 8; ++nt)
      #pragma unroll
      for (int r = 0; r < 4; ++r) ss[r] += vreg[nt][r] * vreg[nt][r];
    #pragma unroll
    for (int r = 0; r < 4; ++r) {
      ss[r] += __shfl_xor(ss[r], 1);
      ss[r] += __shfl_xor(ss[r], 2);
      ss[r] += __shfl_xor(ss[r], 4);
      ss[r] += __shfl_xor(ss[r], 8);
    }
    float sc[4];
    #pragma unroll
    for (int r = 0; r < 4; ++r) sc[r] = ss[r] > 0.f ? rsqrtf(ss[r]) : 1.0f;
    if (EPI == EPI_NORM) {
      unsigned short* op = (unsigned short*)outp;
      #pragma unroll
      for (int nt = 0; nt < 8; ++nt) {
        int col = nt * 16 + (lane & 15);
        #pragma unroll
        for (int r = 0; r < 4; ++r)
          op[(size_t)(rowbase + crow + r) * 128 + col] = f2bf(vreg[nt][r] * sc[r]);
      }
    } else {
      float* op = (float*)outp;
      #pragma unroll
      for (int nt = 0; nt < 8; ++nt) {
        int col = nt * 16 + (lane & 15);
        #pragma unroll
        for (int r = 0; r < 4; ++r) {
          int row = rowbase + crow + r;
          op[(size_t)row * 128 + col] =
              vreg[nt][r] * sc[r] + emb[(size_t)ids[row] * 128 + col];
        }
      }
    }
  }
}

// ---------- CSR aggregation: wave/dst, lane-prefetched edges, 4 gathers in flight ----------
__global__ __launch_bounds__(256) void agg_k(const unsigned short* __restrict__ nsrc,
                                             const int* __restrict__ offs,
                                             const int* __restrict__ srcs_s,
                                             const float* __restrict__ ws_s,
                                             unsigned short* __restrict__ aout, int ndst) {
  int wid = threadIdx.x >> 6, lane = threadIdx.x & 63;
  int d = blockIdx.x * 4 + wid;
  if (d >= ndst) return;
  int beg = offs[d], end = offs[d + 1];
  float ax = 0.f, ay = 0.f, wsum = 0.f;
  for (int base = beg; base < end; base += 64) {
    int cnt = min(64, end - base);
    int sv = 0; float wv = 0.f;
    if (lane < cnt) { sv = srcs_s[base + lane]; wv = ws_s[base + lane]; }
    int j = 0;
    for (; j + 4 <= cnt; j += 4) {
      int s0 = __shfl(sv, j),     s1 = __shfl(sv, j + 1);
      int s2 = __shfl(sv, j + 2), s3 = __shfl(sv, j + 3);
      float w0 = __shfl(wv, j),     w1 = __shfl(wv, j + 1);
      float w2 = __shfl(wv, j + 2), w3 = __shfl(wv, j + 3);
      unsigned u0 = *(const unsigned*)(nsrc + (size_t)s0 * 128 + lane * 2);
      unsigned u1 = *(const unsigned*)(nsrc + (size_t)s1 * 128 + lane * 2);
      unsigned u2 = *(const unsigned*)(nsrc + (size_t)s2 * 128 + lane * 2);
      unsigned u3 = *(const unsigned*)(nsrc + (size_t)s3 * 128 + lane * 2);
      ax += w0 * bf2f((unsigned short)(u0 & 0xffff));
      ay += w0 * bf2f((unsigned short)(u0 >> 16));
      ax += w1 * bf2f((unsigned short)(u1 & 0xffff));
      ay += w1 * bf2f((unsigned short)(u1 >> 16));
      ax += w2 * bf2f((unsigned short)(u2 & 0xffff));
      ay += w2 * bf2f((unsigned short)(u2 >> 16));
      ax += w3 * bf2f((unsigned short)(u3 & 0xffff));
      ay += w3 * bf2f((unsigned short)(u3 >> 16));
      wsum += w0 + w1 + w2 + w3;
    }
    for (; j < cnt; ++j) {
      int s = __shfl(sv, j);
      float w = __shfl(wv, j);
      unsigned u = *(const unsigned*)(nsrc + (size_t)s * 128 + lane * 2);
      ax += w * bf2f((unsigned short)(u & 0xffff));
      ay += w * bf2f((unsigned short)(u >> 16));
      wsum += w;
    }
  }
  float inv = 1.0f / fmaxf(wsum, 1.0f);
  unsigned o = ((unsigned)f2bf(ay * inv) << 16) | (unsigned)f2bf(ax * inv);
  *(unsigned*)(aout + (size_t)d * 128 + lane * 2) = o;
}

// ---------- final scores (bias gathered inline through nids) ----------
__global__ __launch_bounds__(256) void score_k(const float* __restrict__ hitem,
                                               const float* __restrict__ bias,
                                               const int* __restrict__ nids,
                                               const int* __restrict__ ps,
                                               const int* __restrict__ pd,
                                               const int* __restrict__ ns,
                                               const int* __restrict__ nd,
                                               float* __restrict__ out) {
  int wid = threadIdx.x >> 6, lane = threadIdx.x & 63;
  int e = blockIdx.x * 4 + wid;
  if (e >= EP_SZ) return;
  int a = ps[e], b = pd[e], c = ns[e], d = nd[e];
  float2 va = ((const float2*)(hitem + (size_t)a * 128))[lane];
  float2 vb = ((const float2*)(hitem + (size_t)b * 128))[lane];
  float2 vc = ((const float2*)(hitem + (size_t)c * 128))[lane];
  float2 vd = ((const float2*)(hitem + (size_t)d * 128))[lane];
  float dp = va.x * vb.x + va.y * vb.y;
  float dn = vc.x * vd.x + vc.y * vd.y;
  #pragma unroll
  for (int m = 1; m < 64; m <<= 1) {
    dp += __shfl_xor(dp, m);
    dn += __shfl_xor(dn, m);
  }
  if (lane == 0) {
    float sp = dp + bias[nids[a]] + bias[nids[b]];
    float sn = dn + bias[nids[c]] + bias[nids[d]];
    out[e] = fmaxf(sn - sp + 1.0f, 0.0f);
  }
}

extern "C" void kernel_launch(void* const* d_in, const int* in_sizes, int n_in,
                              void* d_out, int out_size, void* d_ws, size_t ws_size,
                              hipStream_t stream) {
  const float* emb  = (const float*)d_in[0];
  const float* bias = (const float*)d_in[1];
  const int* nids   = (const int*)d_in[2];
  const int* src0   = (const int*)d_in[3];
  const int* dst0   = (const int*)d_in[4];
  const float* w0   = (const float*)d_in[5];
  const int* src1   = (const int*)d_in[6];
  const int* dst1   = (const int*)d_in[7];
  const float* w1   = (const float*)d_in[8];
  const int* pos_src = (const int*)d_in[9];
  const int* pos_dst = (const int*)d_in[10];
  const int* neg_src = (const int*)d_in[11];
  const int* neg_dst = (const int*)d_in[12];
  const float* Q0w = (const float*)d_in[13];
  const float* Q0b = (const float*)d_in[14];
  const float* W0w = (const float*)d_in[15];
  const float* W0b = (const float*)d_in[16];
  const float* Q1w = (const float*)d_in[17];
  const float* Q1b = (const float*)d_in[18];
  const float* W1w = (const float*)d_in[19];
  const float* W1b = (const float*)d_in[20];
  float* out = (float*)d_out;

  char* ws = (char*)d_ws;
  size_t p = 0;
  auto carve = [&](size_t sz) { void* r = ws + p; p = (p + sz + 255) & ~(size_t)255; return r; };

  // Region 0: n0 (256 MB) during phase A, reused for phase-B buffers.
  unsigned short* n0 = (unsigned short*)carve((size_t)N0_SZ * 128 * 2);
  unsigned short* h1    = (unsigned short*)(ws + 0);
  unsigned short* n1    = (unsigned short*)(ws + 33554432);
  unsigned short* a1    = (unsigned short*)(ws + 67108864);
  float*          hitem = (float*)(ws + 71303168);

  unsigned short* a0  = (unsigned short*)carve((size_t)N1_SZ * 128 * 2);
  unsigned short* Q0T = (unsigned short*)carve(128 * 128 * 2);
  unsigned short* W0T = (unsigned short*)carve(256 * 128 * 2);
  unsigned short* Q1T = (unsigned short*)carve(128 * 128 * 2);
  unsigned short* W1T = (unsigned short*)carve(256 * 128 * 2);
  // counts0(N1)|counts1(N2)|cursor0(N1)|cursor1(N2) contiguous -> one memset
  int* cnt_all = (int*)carve((size_t)(N1_SZ + N2_SZ) * 2 * 4);
  int* counts  = cnt_all;                       // [0 .. N1+N2)
  int* cursor  = cnt_all + (N1_SZ + N2_SZ);     // cursor0 | cursor1
  int*   offs0   = (int*)carve((N1_SZ + 1) * 4);
  int*   offs1   = (int*)carve((N2_SZ + 1) * 4);
  int*   srcs_s0 = (int*)carve(E0_SZ * 4);
  float* ws_s0   = (float*)carve(E0_SZ * 4);
  int*   srcs_s1 = (int*)carve(E1_SZ * 4);
  float* ws_s1   = (float*)carve(E1_SZ * 4);
  int*   bsums   = (int*)carve(160 * 4);
  (void)ws_size; (void)in_sizes; (void)n_in; (void)out_size;

  hipMemsetAsync(cnt_all, 0, (size_t)(N1_SZ + N2_SZ) * 2 * 4, stream);

  prepw_all_k<<<384, 256, 0, stream>>>(Q0w, W0w, Q1w, W1w, Q0T, W0T, Q1T, W1T);

  // merged CSR build (both layers)
  hist_all_k<<<(E0_SZ + E1_SZ) / 256, 256, 0, stream>>>(dst0, dst1, counts);
  scan_bsums_k<<<(N1_SZ + N2_SZ) / 1024, 256, 0, stream>>>(counts, bsums);
  scan_top2_k<<<2, 256, 0, stream>>>(bsums, offs0 + N1_SZ, offs1 + N2_SZ);
  scan_final_k<<<(N1_SZ + N2_SZ) / 1024, 256, 0, stream>>>(counts, bsums, offs0, offs1);
  scatter_all_k<<<(E0_SZ + E1_SZ) / 256, 256, 0, stream>>>(
      src0, dst0, w0, src1, dst1, w1, offs0, offs1, cursor,
      srcs_s0, ws_s0, srcs_s1, ws_s1);

  // n0 = relu(bf16(emb[nids]) @ Q0 + Q0b)
  gemm_k<1, AM_GATHER, AM_GATHER, EPI_BF16>
      <<<N0_SZ / 64, 256, 0, stream>>>(emb, nullptr, nids, Q0T, Q0b, n0, nullptr);
  // a0 = segsum(w*n0)/max(segsum(w),1)
  agg_k<<<N1_SZ / 4, 256, 0, stream>>>(n0, offs0, srcs_s0, ws_s0, a0, N1_SZ);
  // h1 = rownorm(relu([a0, emb[nids[:N1]]] @ W0 + W0b))
  gemm_k<2, AM_BF16, AM_GATHER, EPI_NORM>
      <<<N1_SZ / 64, 256, 0, stream>>>(a0, emb, nids, W0T, W0b, h1, nullptr);
  // n1 = relu(h1 @ Q1 + Q1b)
  gemm_k<1, AM_BF16, AM_BF16, EPI_BF16>
      <<<N1_SZ / 64, 256, 0, stream>>>(h1, nullptr, nullptr, Q1T, Q1b, n1, nullptr);
  // a1
  agg_k<<<N2_SZ / 4, 256, 0, stream>>>(n1, offs1, srcs_s1, ws_s1, a1, N2_SZ);
  // hitem = rownorm(relu([a1, h1[:N2]] @ W1 + W1b)) + emb[nids[:N2]]
  gemm_k<2, AM_BF16, AM_BF16, EPI_NORM_ADDEMB>
      <<<N2_SZ / 64, 256, 0, stream>>>(a1, h1, nids, W1T, W1b, hitem, emb);

  score_k<<<EP_SZ / 4, 256, 0, stream>>>(hitem, bias, nids, pos_src, pos_dst,
                                         neg_src, neg_dst, out);
}